// Round 3
// baseline (28.629 us; speedup 1.0000x reference)
//
#include <hip/hip_runtime.h>

#define N_SP 2304      // H*W = 48*48
#define C_CH 256
#define B_B  8
#define TILES 36       // N_SP / 64
#define NBLK (B_B * TILES)   // 288
#define BN_EPS 1e-5f

// workspace layout (float offsets)
#define WS_THETA 0                 // 8*2304 = 18432 floats
#define WS_PG    18432             // 288
#define WS_TH    (18432 + 288)     // 288
#define WS_TH2   (18432 + 576)     // 288
#define WS_S     (18432 + 864)     // 8
#define WS_YBAR  (18432 + 872)     // 1
#define WS_SCALE (18432 + 880)     // 256
#define WS_CNT   19568             // int counter (byte offset 78272)

#define AGENT __HIP_MEMORY_SCOPE_AGENT

// K1: per-(b, 64-n tile) projections; 8 waves own 32 channels each.
// Weights read via wave-uniform index -> scalar cache (no LDS in hot loop).
// Last finishing block performs the global finalize (replaces old K2).
__global__ __launch_bounds__(512) void proj_kernel(
    const float* __restrict__ x,
    const float* __restrict__ gw, const float* __restrict__ gb,
    const float* __restrict__ tw, const float* __restrict__ tb,
    const float* __restrict__ pw, const float* __restrict__ pb,
    const float* __restrict__ ww, const float* __restrict__ gamma,
    float* __restrict__ ws, int* __restrict__ cnt)
{
    __shared__ float pt[8][64], pp[8][64], pgv[8][64];
    __shared__ int isLast;

    const int tid  = threadIdx.x;
    const int w    = tid >> 6;
    const int lane = tid & 63;
    const int blk  = blockIdx.x;
    const int b    = blk / TILES;
    const int tile = blk - b * TILES;

    const int n = tile * 64 + lane;
    const float* xp = x + (size_t)b * C_CH * N_SP + (size_t)(w * 32) * N_SP + n;

    float at = 0.f, ap = 0.f, ag = 0.f;
    #pragma unroll
    for (int c = 0; c < 32; ++c) {
        float v = xp[(size_t)c * N_SP];       // 256B coalesced per wave
        const int cc = w * 32 + c;            // wave-uniform -> s_load
        at = fmaf(tw[cc], v, at);
        ap = fmaf(pw[cc], v, ap);
        ag = fmaf(gw[cc], v, ag);
    }
    pt[w][lane]  = at;
    pp[w][lane]  = ap;
    pgv[w][lane] = ag;
    __syncthreads();

    if (tid < 64) {
        float st = 0.f, sp = 0.f, sg = 0.f;
        #pragma unroll
        for (int j = 0; j < 8; ++j) {
            st += pt[j][tid];
            sp += pp[j][tid];
            sg += pgv[j][tid];
        }
        const float th = st + tb[0];
        const float ph = sp + pb[0];
        const float gg = sg + gb[0];

        ws[WS_THETA + b * N_SP + tile * 64 + tid] = th;

        float r_pg  = ph * gg;
        float r_th  = th;
        float r_th2 = th * th;
        #pragma unroll
        for (int off = 32; off >= 1; off >>= 1) {
            r_pg  += __shfl_xor(r_pg,  off, 64);
            r_th  += __shfl_xor(r_th,  off, 64);
            r_th2 += __shfl_xor(r_th2, off, 64);
        }
        if (tid == 0) {
            // agent-scope stores: land at a coherence point visible across XCDs
            __hip_atomic_store(&ws[WS_PG  + blk], r_pg,  __ATOMIC_RELAXED, AGENT);
            __hip_atomic_store(&ws[WS_TH  + blk], r_th,  __ATOMIC_RELAXED, AGENT);
            __hip_atomic_store(&ws[WS_TH2 + blk], r_th2, __ATOMIC_RELAXED, AGENT);
        }
    }
    __syncthreads();

    if (tid == 0) {
        int old = __hip_atomic_fetch_add(cnt, 1, __ATOMIC_ACQ_REL, AGENT);
        isLast = (old == NBLK - 1);
    }
    __syncthreads();
    if (!isLast) return;

    // ---- finalize (old K2), run by the last block only ----
    __shared__ float fS[B_B], fTH[B_B], fTH2[B_B];
    {
        const int fb = tid >> 6;        // 0..7
        const int l  = tid & 63;
        float pg = 0.f, th = 0.f, th2 = 0.f;
        if (l < TILES) {
            pg  = __hip_atomic_load(&ws[WS_PG  + fb * TILES + l], __ATOMIC_RELAXED, AGENT);
            th  = __hip_atomic_load(&ws[WS_TH  + fb * TILES + l], __ATOMIC_RELAXED, AGENT);
            th2 = __hip_atomic_load(&ws[WS_TH2 + fb * TILES + l], __ATOMIC_RELAXED, AGENT);
        }
        #pragma unroll
        for (int off = 32; off >= 1; off >>= 1) {
            pg  += __shfl_xor(pg,  off, 64);
            th  += __shfl_xor(th,  off, 64);
            th2 += __shfl_xor(th2, off, 64);
        }
        if (l == 0) {
            fS[fb]   = pg / (float)N_SP;   // s_b
            fTH[fb]  = th;
            fTH2[fb] = th2;
        }
    }
    __syncthreads();

    if (tid < C_CH) {
        float ybar = 0.f, ey2 = 0.f;
        #pragma unroll
        for (int bb = 0; bb < B_B; ++bb) {
            ybar += fS[bb] * fTH[bb];
            ey2  += fS[bb] * fS[bb] * fTH2[bb];
        }
        const float inv = 1.0f / (float)(B_B * N_SP);
        ybar *= inv;
        ey2  *= inv;
        const float vary = ey2 - ybar * ybar;

        const float wv = ww[tid];
        ws[WS_SCALE + tid] = gamma[tid] * wv * rsqrtf(wv * wv * vary + BN_EPS);

        if (tid < B_B) ws[WS_S + tid] = fS[tid];
        if (tid == 0)  ws[WS_YBAR]    = ybar;
    }
}

// K3: out[b,c,n] = x + beta[c] + scale[c]*(theta[b,n]*s_b - ybar)
// one block per (b,c) row; 192 threads x 3 float4 = 2304 floats exactly.
__global__ __launch_bounds__(192) void out_kernel(
    const float* __restrict__ x, const float* __restrict__ beta,
    const float* __restrict__ ws, float* __restrict__ out)
{
    const int bc = blockIdx.x;       // b*256 + c
    const int b  = bc >> 8;
    const int c  = bc & 255;

    const float s  = ws[WS_S + b];
    const float yb = ws[WS_YBAR];
    const float sc = ws[WS_SCALE + c];
    const float be = beta[c];

    const float4* xr   = (const float4*)(x  + (size_t)bc * N_SP);
    const float4* tr   = (const float4*)(ws + WS_THETA + b * N_SP);
    float4*       orow = (float4*)((float*)out + (size_t)bc * N_SP);

    #pragma unroll
    for (int k = 0; k < 3; ++k) {
        const int i = threadIdx.x + k * 192;
        float4 xv = xr[i];
        float4 tv = tr[i];
        float4 o;
        o.x = fmaf(sc, fmaf(tv.x, s, -yb), xv.x + be);
        o.y = fmaf(sc, fmaf(tv.y, s, -yb), xv.y + be);
        o.z = fmaf(sc, fmaf(tv.z, s, -yb), xv.z + be);
        o.w = fmaf(sc, fmaf(tv.w, s, -yb), xv.w + be);
        orow[i] = o;
    }
}

extern "C" void kernel_launch(void* const* d_in, const int* in_sizes, int n_in,
                              void* d_out, int out_size, void* d_ws, size_t ws_size,
                              hipStream_t stream) {
    const float* x        = (const float*)d_in[0];
    const float* g_w      = (const float*)d_in[1];
    const float* g_b      = (const float*)d_in[2];
    const float* theta_w  = (const float*)d_in[3];
    const float* theta_b  = (const float*)d_in[4];
    const float* phi_w    = (const float*)d_in[5];
    const float* phi_b    = (const float*)d_in[6];
    const float* w_w      = (const float*)d_in[7];
    // d_in[8] = w_b : cancels in training-mode BatchNorm (mean subtraction)
    const float* bn_gamma = (const float*)d_in[9];
    const float* bn_beta  = (const float*)d_in[10];

    float* ws  = (float*)d_ws;
    float* out = (float*)d_out;
    int*   cnt = (int*)((char*)d_ws + WS_CNT * sizeof(float));

    hipMemsetAsync(cnt, 0, sizeof(int), stream);
    proj_kernel<<<NBLK, 512, 0, stream>>>(x, g_w, g_b, theta_w, theta_b,
                                          phi_w, phi_b, w_w, bn_gamma, ws, cnt);
    out_kernel<<<B_B * C_CH, 192, 0, stream>>>(x, bn_beta, ws, out);
}

// Round 4
// 17.160 us; speedup vs baseline: 1.6683x; 1.6683x over previous
//
#include <hip/hip_runtime.h>

#define N_SP 2304      // H*W = 48*48
#define C_CH 256
#define B_B  8
#define TILES 36       // N_SP / 64
#define BN_EPS 1e-5f

// workspace layout (float offsets)
#define WS_THETA 0                 // 8*2304 = 18432 floats
#define WS_PG    18432             // 288
#define WS_TH    (18432 + 288)     // 288
#define WS_TH2   (18432 + 576)     // 288

// K1: per-(b, 64-n tile) projections. 8 waves each own a 32-channel chunk;
// LDS cross-wave reduce; wave 0 finishes (theta store + partial sums).
// (identical to the measured-good R1 version)
__global__ __launch_bounds__(512) void proj_kernel(
    const float* __restrict__ x,
    const float* __restrict__ gw, const float* __restrict__ gb,
    const float* __restrict__ tw, const float* __restrict__ tb,
    const float* __restrict__ pw, const float* __restrict__ pb,
    float* __restrict__ ws)
{
    __shared__ float s_tw[C_CH], s_pw[C_CH], s_gw[C_CH];
    __shared__ float pt[8][64], pp[8][64], pgv[8][64];

    const int tid  = threadIdx.x;
    const int w    = tid >> 6;
    const int lane = tid & 63;
    const int blk  = blockIdx.x;
    const int b    = blk / TILES;
    const int tile = blk - b * TILES;

    if (tid < C_CH) {
        s_tw[tid] = tw[tid];
        s_pw[tid] = pw[tid];
        s_gw[tid] = gw[tid];
    }
    __syncthreads();

    const int n = tile * 64 + lane;
    const float* xp = x + (size_t)b * C_CH * N_SP + (size_t)(w * 32) * N_SP + n;

    float at = 0.f, ap = 0.f, ag = 0.f;
    #pragma unroll
    for (int c = 0; c < 32; ++c) {
        float v = xp[(size_t)c * N_SP];           // 256B coalesced per wave
        const int cc = w * 32 + c;
        at = fmaf(s_tw[cc], v, at);               // LDS broadcast reads
        ap = fmaf(s_pw[cc], v, ap);
        ag = fmaf(s_gw[cc], v, ag);
    }
    pt[w][lane]  = at;
    pp[w][lane]  = ap;
    pgv[w][lane] = ag;
    __syncthreads();

    if (tid < 64) {
        float st = 0.f, sp = 0.f, sg = 0.f;
        #pragma unroll
        for (int j = 0; j < 8; ++j) {
            st += pt[j][tid];
            sp += pp[j][tid];
            sg += pgv[j][tid];
        }
        const float th = st + tb[0];
        const float ph = sp + pb[0];
        const float gg = sg + gb[0];

        ws[WS_THETA + b * N_SP + tile * 64 + tid] = th;

        float r_pg  = ph * gg;
        float r_th  = th;
        float r_th2 = th * th;
        #pragma unroll
        for (int off = 32; off >= 1; off >>= 1) {
            r_pg  += __shfl_xor(r_pg,  off, 64);
            r_th  += __shfl_xor(r_th,  off, 64);
            r_th2 += __shfl_xor(r_th2, off, 64);
        }
        if (tid == 0) {
            ws[WS_PG  + blk] = r_pg;
            ws[WS_TH  + blk] = r_th;
            ws[WS_TH2 + blk] = r_th2;
        }
    }
}

// K3: redundant per-block finalize prologue (partials are L2-hot), then
// out[b,c,n] = x + beta[c] + scale[c]*(theta[b,n]*s_b - ybar).
// one block per (b,c) row; 192 threads x 3 float4 = 2304 floats exactly.
__global__ __launch_bounds__(192) void out_kernel(
    const float* __restrict__ x,  const float* __restrict__ ww,
    const float* __restrict__ gamma, const float* __restrict__ beta,
    const float* __restrict__ ws, float* __restrict__ out)
{
    __shared__ float fS[B_B], fTH[B_B], fTH2[B_B];
    const int tid = threadIdx.x;

    // ---- finalize prologue: wave 0 reduces the 3x288 partials ----
    if (tid < 64) {
        const int fb = tid >> 3;        // 8 groups of 8 lanes
        const int l  = tid & 7;
        float pg = 0.f, th = 0.f, th2 = 0.f;
        #pragma unroll
        for (int k = 0; k < 5; ++k) {
            const int t = l + 8 * k;
            if (t < TILES) {
                pg  += ws[WS_PG  + fb * TILES + t];
                th  += ws[WS_TH  + fb * TILES + t];
                th2 += ws[WS_TH2 + fb * TILES + t];
            }
        }
        #pragma unroll
        for (int off = 4; off >= 1; off >>= 1) {
            pg  += __shfl_xor(pg,  off, 64);
            th  += __shfl_xor(th,  off, 64);
            th2 += __shfl_xor(th2, off, 64);
        }
        if (l == 0) {
            fS[fb]   = pg / (float)N_SP;   // s_b
            fTH[fb]  = th;
            fTH2[fb] = th2;
        }
    }
    __syncthreads();

    const int bc = blockIdx.x;       // b*256 + c
    const int b  = bc >> 8;
    const int c  = bc & 255;

    float ybar = 0.f, ey2 = 0.f;
    #pragma unroll
    for (int bb = 0; bb < B_B; ++bb) {
        ybar += fS[bb] * fTH[bb];     // LDS broadcast reads
        ey2  += fS[bb] * fS[bb] * fTH2[bb];
    }
    const float inv = 1.0f / (float)(B_B * N_SP);
    ybar *= inv;
    ey2  *= inv;
    const float vary = ey2 - ybar * ybar;

    const float wv = ww[c];          // block-uniform -> scalar loads
    const float sc = gamma[c] * wv * rsqrtf(wv * wv * vary + BN_EPS);
    const float s  = fS[b];
    const float be = beta[c];
    const float yb = ybar;

    const float4* xr   = (const float4*)(x  + (size_t)bc * N_SP);
    const float4* tr   = (const float4*)(ws + WS_THETA + b * N_SP);
    float4*       orow = (float4*)((float*)out + (size_t)bc * N_SP);

    #pragma unroll
    for (int k = 0; k < 3; ++k) {
        const int i = tid + k * 192;
        float4 xv = xr[i];
        float4 tv = tr[i];
        float4 o;
        o.x = fmaf(sc, fmaf(tv.x, s, -yb), xv.x + be);
        o.y = fmaf(sc, fmaf(tv.y, s, -yb), xv.y + be);
        o.z = fmaf(sc, fmaf(tv.z, s, -yb), xv.z + be);
        o.w = fmaf(sc, fmaf(tv.w, s, -yb), xv.w + be);
        orow[i] = o;
    }
}

extern "C" void kernel_launch(void* const* d_in, const int* in_sizes, int n_in,
                              void* d_out, int out_size, void* d_ws, size_t ws_size,
                              hipStream_t stream) {
    const float* x        = (const float*)d_in[0];
    const float* g_w      = (const float*)d_in[1];
    const float* g_b      = (const float*)d_in[2];
    const float* theta_w  = (const float*)d_in[3];
    const float* theta_b  = (const float*)d_in[4];
    const float* phi_w    = (const float*)d_in[5];
    const float* phi_b    = (const float*)d_in[6];
    const float* w_w      = (const float*)d_in[7];
    // d_in[8] = w_b : cancels in training-mode BatchNorm (mean subtraction)
    const float* bn_gamma = (const float*)d_in[9];
    const float* bn_beta  = (const float*)d_in[10];

    float* ws  = (float*)d_ws;
    float* out = (float*)d_out;

    proj_kernel<<<B_B * TILES, 512, 0, stream>>>(x, g_w, g_b, theta_w, theta_b,
                                                 phi_w, phi_b, ws);
    out_kernel<<<B_B * C_CH, 192, 0, stream>>>(x, w_w, bn_gamma, bn_beta, ws, out);
}

// Round 5
// 17.120 us; speedup vs baseline: 1.6722x; 1.0023x over previous
//
#include <hip/hip_runtime.h>

#define N_SP 2304      // H*W = 48*48
#define C_CH 256
#define B_B  8
#define TILES 36       // N_SP / 64
#define BN_EPS 1e-5f

// workspace layout (float offsets)
#define WS_THETA 0                 // 8*2304 = 18432 floats
#define WS_PG    18432             // 288
#define WS_TH    (18432 + 288)     // 288
#define WS_TH2   (18432 + 576)     // 288

// K1: per-(b, 64-n tile) projections. 8 waves each own a 32-channel chunk.
// Weights read through the SCALAR pipe (readfirstlane-forced uniform index
// -> s_load), removing 96 LDS reads/wave + the staging barrier vs R3.
__global__ __launch_bounds__(512) void proj_kernel(
    const float* __restrict__ x,
    const float* __restrict__ gw, const float* __restrict__ gb,
    const float* __restrict__ tw, const float* __restrict__ tb,
    const float* __restrict__ pw, const float* __restrict__ pb,
    float* __restrict__ ws)
{
    __shared__ float pt[8][64], pp[8][64], pgv[8][64];

    const int tid  = threadIdx.x;
    const int w    = tid >> 6;
    const int lane = tid & 63;
    const int blk  = blockIdx.x;
    const int b    = blk / TILES;
    const int tile = blk - b * TILES;

    const int n = tile * 64 + lane;
    const int cbase = __builtin_amdgcn_readfirstlane(w * 32);   // SGPR
    const float* xp = x + (size_t)b * C_CH * N_SP + (size_t)cbase * N_SP + n;

    float at = 0.f, ap = 0.f, ag = 0.f;
    #pragma unroll
    for (int c = 0; c < 32; ++c) {
        float v = xp[(size_t)c * N_SP];           // 256B coalesced per wave
        at = fmaf(tw[cbase + c], v, at);          // s_load (scalar cache)
        ap = fmaf(pw[cbase + c], v, ap);
        ag = fmaf(gw[cbase + c], v, ag);
    }
    pt[w][lane]  = at;
    pp[w][lane]  = ap;
    pgv[w][lane] = ag;
    __syncthreads();

    if (tid < 64) {
        float st = 0.f, sp = 0.f, sg = 0.f;
        #pragma unroll
        for (int j = 0; j < 8; ++j) {
            st += pt[j][tid];
            sp += pp[j][tid];
            sg += pgv[j][tid];
        }
        const float th = st + tb[0];
        const float ph = sp + pb[0];
        const float gg = sg + gb[0];

        ws[WS_THETA + b * N_SP + tile * 64 + tid] = th;

        float r_pg  = ph * gg;
        float r_th  = th;
        float r_th2 = th * th;
        #pragma unroll
        for (int off = 32; off >= 1; off >>= 1) {
            r_pg  += __shfl_xor(r_pg,  off, 64);
            r_th  += __shfl_xor(r_th,  off, 64);
            r_th2 += __shfl_xor(r_th2, off, 64);
        }
        if (tid == 0) {
            ws[WS_PG  + blk] = r_pg;
            ws[WS_TH  + blk] = r_th;
            ws[WS_TH2 + blk] = r_th2;
        }
    }
}

// K3: redundant per-block finalize prologue (partials are L2-hot), then
// out[b,c,n] = x + beta[c] + scale[c]*(theta[b,n]*s_b - ybar).
// one block per (b,c) row; 192 threads x 3 float4 = 2304 floats exactly.
// (byte-identical to the measured-good R3 version)
__global__ __launch_bounds__(192) void out_kernel(
    const float* __restrict__ x,  const float* __restrict__ ww,
    const float* __restrict__ gamma, const float* __restrict__ beta,
    const float* __restrict__ ws, float* __restrict__ out)
{
    __shared__ float fS[B_B], fTH[B_B], fTH2[B_B];
    const int tid = threadIdx.x;

    // ---- finalize prologue: wave 0 reduces the 3x288 partials ----
    if (tid < 64) {
        const int fb = tid >> 3;        // 8 groups of 8 lanes
        const int l  = tid & 7;
        float pg = 0.f, th = 0.f, th2 = 0.f;
        #pragma unroll
        for (int k = 0; k < 5; ++k) {
            const int t = l + 8 * k;
            if (t < TILES) {
                pg  += ws[WS_PG  + fb * TILES + t];
                th  += ws[WS_TH  + fb * TILES + t];
                th2 += ws[WS_TH2 + fb * TILES + t];
            }
        }
        #pragma unroll
        for (int off = 4; off >= 1; off >>= 1) {
            pg  += __shfl_xor(pg,  off, 64);
            th  += __shfl_xor(th,  off, 64);
            th2 += __shfl_xor(th2, off, 64);
        }
        if (l == 0) {
            fS[fb]   = pg / (float)N_SP;   // s_b
            fTH[fb]  = th;
            fTH2[fb] = th2;
        }
    }
    __syncthreads();

    const int bc = blockIdx.x;       // b*256 + c
    const int b  = bc >> 8;
    const int c  = bc & 255;

    float ybar = 0.f, ey2 = 0.f;
    #pragma unroll
    for (int bb = 0; bb < B_B; ++bb) {
        ybar += fS[bb] * fTH[bb];     // LDS broadcast reads
        ey2  += fS[bb] * fS[bb] * fTH2[bb];
    }
    const float inv = 1.0f / (float)(B_B * N_SP);
    ybar *= inv;
    ey2  *= inv;
    const float vary = ey2 - ybar * ybar;

    const float wv = ww[c];          // block-uniform -> scalar loads
    const float sc = gamma[c] * wv * rsqrtf(wv * wv * vary + BN_EPS);
    const float s  = fS[b];
    const float be = beta[c];
    const float yb = ybar;

    const float4* xr   = (const float4*)(x  + (size_t)bc * N_SP);
    const float4* tr   = (const float4*)(ws + WS_THETA + b * N_SP);
    float4*       orow = (float4*)((float*)out + (size_t)bc * N_SP);

    #pragma unroll
    for (int k = 0; k < 3; ++k) {
        const int i = tid + k * 192;
        float4 xv = xr[i];
        float4 tv = tr[i];
        float4 o;
        o.x = fmaf(sc, fmaf(tv.x, s, -yb), xv.x + be);
        o.y = fmaf(sc, fmaf(tv.y, s, -yb), xv.y + be);
        o.z = fmaf(sc, fmaf(tv.z, s, -yb), xv.z + be);
        o.w = fmaf(sc, fmaf(tv.w, s, -yb), xv.w + be);
        orow[i] = o;
    }
}

extern "C" void kernel_launch(void* const* d_in, const int* in_sizes, int n_in,
                              void* d_out, int out_size, void* d_ws, size_t ws_size,
                              hipStream_t stream) {
    const float* x        = (const float*)d_in[0];
    const float* g_w      = (const float*)d_in[1];
    const float* g_b      = (const float*)d_in[2];
    const float* theta_w  = (const float*)d_in[3];
    const float* theta_b  = (const float*)d_in[4];
    const float* phi_w    = (const float*)d_in[5];
    const float* phi_b    = (const float*)d_in[6];
    const float* w_w      = (const float*)d_in[7];
    // d_in[8] = w_b : cancels in training-mode BatchNorm (mean subtraction)
    const float* bn_gamma = (const float*)d_in[9];
    const float* bn_beta  = (const float*)d_in[10];

    float* ws  = (float*)d_ws;
    float* out = (float*)d_out;

    proj_kernel<<<B_B * TILES, 512, 0, stream>>>(x, g_w, g_b, theta_w, theta_b,
                                                 phi_w, phi_b, ws);
    out_kernel<<<B_B * C_CH, 192, 0, stream>>>(x, w_w, bn_gamma, bn_beta, ws, out);
}